// Round 8
// baseline (254.123 us; speedup 1.0000x reference)
//
#include <hip/hip_runtime.h>
#include <cstdint>
#include <cstddef>

// ---------------------------------------------------------------------------
// RelativeSelfAttention  (b=2, s=2048, d=1024, H=16, hd=64, REL_W=128 -> 257)
//   1. cvt_all: x, w_qkv, w_rel  f32 -> f16
//   2. qkv_gemm: -> q[b,h,s,64], k[b,h,s,64], v[b,h,s,64] (row-major)
//   3. vtrans:  v -> vT[b,h,64,s]
//   4. rel_proj: rel[b,h,s,257] = (q @ w_rel^T + b_rel) * log2e  (f16)
//   5. attn: flash, swapped-operand, 32x32x16 MFMA (m214-proven shape):
//        wave = 32 q-rows; Sᵀ=mfma(K,Q) col=q=lane&31; softmax 31-op tree +
//        ONE shfl_xor(32); defer-max; P via wave-private padded lP[32][72];
//        Oᵀ=mfma(Vᵀ,P). KVBLK=64, dbuf gload_lds staging, XCD-clustered bh.
// ---------------------------------------------------------------------------

#define DEV __device__ __forceinline__
using u16    = unsigned short;
using f16x8  = __attribute__((ext_vector_type(8))) _Float16;
using f32x4  = __attribute__((ext_vector_type(4))) float;
using f32x16 = __attribute__((ext_vector_type(16))) float;

DEV f32x4 mfma16(f16x8 a, f16x8 b, f32x4 c) {
  return __builtin_amdgcn_mfma_f32_16x16x32_f16(a, b, c, 0, 0, 0);
}
DEV f32x16 mfma32(f16x8 a, f16x8 b, f32x16 c) {
  return __builtin_amdgcn_mfma_f32_32x32x16_f16(a, b, c, 0, 0, 0);
}
DEV void gload16(const void* g, const void* l) {
  __builtin_amdgcn_global_load_lds((const __attribute__((address_space(1))) void*)g,
                                   (__attribute__((address_space(3))) void*)l,
                                   16, 0, 0);
}
DEV u16 f2h(float f) { _Float16 h = (_Float16)f; return __builtin_bit_cast(u16, h); }
DEV float h2f(u16 u) { return (float)__builtin_bit_cast(_Float16, u); }
DEV uint32_t pkrtz(float a, float b) {
  auto h = __builtin_amdgcn_cvt_pkrtz(a, b);
  return __builtin_bit_cast(uint32_t, h);
}

#if __has_builtin(__builtin_amdgcn_exp2f)
#define EXP2(x) __builtin_amdgcn_exp2f(x)
#else
#define EXP2(x) __expf((x) * 0.6931471805599453f)
#endif
#define LOG2E 1.4426950408889634f

// ---------------------------------------------------------------------------
__global__ __launch_bounds__(256) void cvt_all(
    const float* __restrict__ x, const float* __restrict__ wq,
    const float* __restrict__ wr, u16* __restrict__ xb,
    u16* __restrict__ wb, u16* __restrict__ wrelb) {
  int i = (blockIdx.x * 256 + threadIdx.x) * 4;
  if (i < 4194304) {
    float4 v = *(const float4*)(x + i);
    uint32_t a = f2h(v.x) | ((uint32_t)f2h(v.y) << 16);
    uint32_t b = f2h(v.z) | ((uint32_t)f2h(v.w) << 16);
    *(uint2*)(xb + i) = make_uint2(a, b);
  } else if (i < 7340032) {
    int j = i - 4194304;
    float4 v = *(const float4*)(wq + j);
    uint32_t a = f2h(v.x) | ((uint32_t)f2h(v.y) << 16);
    uint32_t b = f2h(v.z) | ((uint32_t)f2h(v.w) << 16);
    *(uint2*)(wb + j) = make_uint2(a, b);
  } else if (i < 7357440) {
    int j = i - 7340032;
#pragma unroll
    for (int e = 0; e < 4; ++e) {
      int r = (j + e) >> 6, c = (j + e) & 63;
      wrelb[j + e] = (r < 257) ? f2h(wr[r * 64 + c]) : (u16)0;
    }
  }
}

// ---------------------------------------------------------------------------
// QKV GEMM (m97 structure + XCD swizzle). All three outputs row-major.
__global__ __launch_bounds__(256) void qkv_gemm(
    const u16* __restrict__ xb, const u16* __restrict__ wb,
    const float* __restrict__ bqkv,
    u16* __restrict__ qb, u16* __restrict__ kb, u16* __restrict__ vb) {
  __shared__ __align__(16) u16 lA[128 * 32];
  __shared__ __align__(16) u16 lB[128 * 32];
  const int tid = threadIdx.x, l = tid & 63, w = tid >> 6;
  const int lr = l & 15, lg = l >> 4;
  const int sw = (blockIdx.x & 7) * 96 + (blockIdx.x >> 3);
  const int m0 = (sw / 24) * 128, n0 = (sw % 24) * 128;
  const int wm = w >> 1, wn = w & 1;
  const int srow = l >> 2, scol = (l & 3) * 8;
  f32x4 acc[4][4] = {};
  for (int k0 = 0; k0 < 1024; k0 += 32) {
    __syncthreads();
#pragma unroll
    for (int r = 0; r < 2; ++r) {
      const int row = r * 64 + w * 16 + srow;
      gload16(xb + (size_t)(m0 + row) * 1024 + k0 + scol,
              (const char*)lA + r * 4096 + w * 1024);
      gload16(wb + (size_t)(n0 + row) * 1024 + k0 + scol,
              (const char*)lB + r * 4096 + w * 1024);
    }
    __syncthreads();
    f16x8 af[4], bfr[4];
#pragma unroll
    for (int mf = 0; mf < 4; ++mf)
      af[mf] = *(const f16x8*)((const char*)lA + (wm * 64 + mf * 16 + lr) * 64 + lg * 16);
#pragma unroll
    for (int nf = 0; nf < 4; ++nf)
      bfr[nf] = *(const f16x8*)((const char*)lB + (wn * 64 + nf * 16 + lr) * 64 + lg * 16);
#pragma unroll
    for (int mf = 0; mf < 4; ++mf)
#pragma unroll
      for (int nf = 0; nf < 4; ++nf)
        acc[mf][nf] = mfma16(af[mf], bfr[nf], acc[mf][nf]);
  }
#pragma unroll
  for (int nf = 0; nf < 4; ++nf) {
    const int cg = n0 + wn * 64 + nf * 16 + lr;
    const int h = cg / 192, t = (cg % 192) >> 6, c = cg & 63;
    const float bias = bqkv[cg];
    u16* dst = (t == 0) ? qb : (t == 1) ? kb : vb;
#pragma unroll
    for (int mf = 0; mf < 4; ++mf) {
#pragma unroll
      for (int j = 0; j < 4; ++j) {
        const int rg = m0 + wm * 64 + mf * 16 + lg * 4 + j;
        const int bb = rg >> 11, sr = rg & 2047;
        const int bh = bb * 16 + h;
        dst[((size_t)bh * 2048 + sr) * 64 + c] = f2h(acc[mf][nf][j] + bias);
      }
    }
  }
}

// ---------------------------------------------------------------------------
// v[b,h,s,64] -> vT[b,h,64,s].  grid 512 = 32 bh x 16 s-blocks of 128.
__global__ __launch_bounds__(256) void vtrans(const u16* __restrict__ vb,
                                              u16* __restrict__ vtb) {
  __shared__ u16 t[128][68];
  const int tid = threadIdx.x;
  const int bh = blockIdx.x >> 4, s0 = (blockIdx.x & 15) * 128;
  const u16* src = vb + ((size_t)bh * 2048 + s0) * 64;
#pragma unroll
  for (int it = 0; it < 8; ++it) {
    const int r = it * 16 + (tid >> 4), c = (tid & 15) * 4;
    *(uint2*)&t[r][c] = *(const uint2*)(src + r * 64 + c);
  }
  __syncthreads();
  const int w = tid >> 6, l = tid & 63;
#pragma unroll
  for (int dd = 0; dd < 16; ++dd) {
    const int d = dd * 4 + w;
    u16* dst = vtb + ((size_t)bh * 64 + d) * 2048 + s0;
#pragma unroll
    for (int sh = 0; sh < 2; ++sh)
      dst[sh * 64 + l] = t[sh * 64 + l][d];
  }
}

// ---------------------------------------------------------------------------
// rel[b,h,s,257] = (q @ w_rel^T + b_rel) * LOG2E  (f16, pre-scaled for exp2)
__global__ __launch_bounds__(256) void rel_proj(
    const u16* __restrict__ qb, const u16* __restrict__ wrelb,
    const float* __restrict__ brel, u16* __restrict__ relb) {
  __shared__ __align__(16) u16 lw[272 * 72];
  const int tid = threadIdx.x, l = tid & 63, w = tid >> 6;
  const int lr = l & 15, lg = l >> 4;
  for (int i = tid; i < 272 * 8; i += 256) {
    const int r = i >> 3, c = i & 7;
    *(f16x8*)(lw + r * 72 + c * 8) = *(const f16x8*)(wrelb + r * 64 + c * 8);
  }
  __syncthreads();
  const int row0 = blockIdx.x * 64 + w * 16;
  f16x8 aq[2];
#pragma unroll
  for (int kk = 0; kk < 2; ++kk)
    aq[kk] = *(const f16x8*)(qb + (size_t)(row0 + lr) * 64 + kk * 32 + lg * 8);
  f32x4 acc[17] = {};
#pragma unroll
  for (int nt = 0; nt < 17; ++nt)
#pragma unroll
    for (int kk = 0; kk < 2; ++kk) {
      f16x8 bfr = *(const f16x8*)(lw + (nt * 16 + lr) * 72 + kk * 32 + lg * 8);
      acc[nt] = mfma16(aq[kk], bfr, acc[nt]);
    }
#pragma unroll
  for (int nt = 0; nt < 17; ++nt) {
    const int cg = nt * 16 + lr;
    if (cg < 257) {
      const float bias = brel[cg];
#pragma unroll
      for (int j = 0; j < 4; ++j) {
        const int rg = row0 + lg * 4 + j;
        relb[(size_t)rg * 257 + cg] = f2h((acc[nt][j] + bias) * LOG2E);
      }
    }
  }
}

// ---------------------------------------------------------------------------
// Flash attention, 32x32x16 MFMA, swapped-operand. grid 512, 4 waves/block.
// Wave owns 32 q-rows (q = lane&31). C-layout (32x32): col=lane&31,
// row=(reg&3)+8*(reg>>2)+4*(lane>>5). A/B frag: 8 f16, k=(lane>>5)*8+e.
__global__ __launch_bounds__(256) void attn_kernel(
    const u16* __restrict__ qb, const u16* __restrict__ kb,
    const u16* __restrict__ vtb, const u16* __restrict__ relb,
    float* __restrict__ out) {
  __shared__ __align__(16) u16 lK[2][64 * 64];   // [key][dim], src-swizzled
  __shared__ __align__(16) u16 lV[2][64 * 64];   // [dim][key], src-swizzled
  __shared__ __align__(16) u16 lP[4][32 * 72];   // per-wave [q][key pad 72]
  const int tid = threadIdx.x, l = tid & 63, w = tid >> 6;
  const int q = l & 31, hi = l >> 5;
  // XCD clustering: xcd = bid&7 owns bh in [xcd*4, xcd*4+4)
  const int bid = blockIdx.x;
  const int i8 = bid >> 3;                 // 0..63
  const int bh = (bid & 7) * 4 + (i8 & 3);
  const int q0 = (i8 >> 2) * 128 + w * 32; // wave's q rows [q0, q0+31]
  const int qrow = q0 + q;                 // THIS lane's q row
  const float CS = 0.125f * LOG2E;

  f16x8 aq[4];  // Q as B-operand: B[k=dim win][col=q]; win kkw: dims kkw*16+hi*8
#pragma unroll
  for (int kkw = 0; kkw < 4; ++kkw)
    aq[kkw] = *(const f16x8*)(qb + ((size_t)bh * 2048 + qrow) * 64 + kkw * 16 + hi * 8);

  const u16* relrow = relb + ((size_t)bh * 2048 + qrow) * 257;
  const float cL = h2f(relrow[0]), cR = h2f(relrow[256]);

  float mi = -1e30f, li = 0.f;   // li = per-lane partial (partner-summed at end)
  f32x16 oacc[2] = {};           // O^T tiles: dims [0,32) and [32,64), col=q

  u16* lPw = lP[w];
  const int sn = w * 8 + (l >> 3);
  const int sc = (l & 7) ^ (l >> 3);  // pre-swizzled source chunk (rule #21)

  auto STAGE = [&](int nb, int kt) {
    const int key0 = kt * 64;
#pragma unroll
    for (int r = 0; r < 2; ++r) {
      const int n = r * 32 + sn;
      gload16(kb + ((size_t)bh * 2048 + key0 + n) * 64 + sc * 8,
              (const char*)lK + nb * 8192 + r * 4096 + w * 1024);
      gload16(vtb + ((size_t)(bh * 64 + n)) * 2048 + key0 + sc * 8,
              (const char*)lV + nb * 8192 + r * 4096 + w * 1024);
    }
  };

  int cur = 0;
  STAGE(0, 0);
  for (int kt = 0; kt < 32; ++kt) {
    __syncthreads();                      // buf[cur] ready (drains vmcnt)
    if (kt < 31) STAGE(cur ^ 1, kt + 1);  // prefetch next tile

    const char* Kb = (const char*)lK + cur * 8192;
    const char* Vb = (const char*)lV + cur * 8192;
    const int key0 = kt * 64;

    // S^T = K x Q : sa[s][m] = score[key = key0+s*32+(m&3)+8*(m>>2)+4*hi][q]
    f32x16 sa[2] = {};
    __builtin_amdgcn_s_setprio(1);
#pragma unroll
    for (int s = 0; s < 2; ++s)
#pragma unroll
      for (int kkw = 0; kkw < 4; ++kkw) {
        f16x8 ak = *(const f16x8*)(Kb + (s * 32 + q) * 128 +
                                   (((kkw * 2 + hi) ^ (l & 7)) * 16));
        sa[s] = mfma32(ak, aq[kkw], sa[s]);
      }
    __builtin_amdgcn_s_setprio(0);

    // rel bias (band classification; wave rows [q0, q0+31])
    if (key0 <= q0 - 192) {
#pragma unroll
      for (int s = 0; s < 2; ++s)
#pragma unroll
        for (int m = 0; m < 16; ++m) sa[s][m] = sa[s][m] * CS + cL;
    } else if (key0 >= q0 + 160) {
#pragma unroll
      for (int s = 0; s < 2; ++s)
#pragma unroll
        for (int m = 0; m < 16; ++m) sa[s][m] = sa[s][m] * CS + cR;
    } else {
#pragma unroll
      for (int s = 0; s < 2; ++s)
#pragma unroll
        for (int m = 0; m < 16; ++m) {
          const int key = key0 + s * 32 + (m & 3) + 8 * (m >> 2) + 4 * hi;
          int off = key - qrow;
          off = off < -128 ? -128 : (off > 128 ? 128 : off);
          sa[s][m] = sa[s][m] * CS + h2f(relrow[off + 128]);
        }
    }

    // online softmax: 31-op in-reg max tree + ONE cross-lane shfl
    float pm = -1e30f;
#pragma unroll
    for (int s = 0; s < 2; ++s)
#pragma unroll
      for (int m = 0; m < 16; ++m) pm = fmaxf(pm, sa[s][m]);
    pm = fmaxf(pm, __shfl_xor(pm, 32));
    if (!__all(pm - mi <= 8.f)) {         // defer-max
      const float mnew = fmaxf(mi, pm);
      const float a = EXP2(mi - mnew);
      li *= a;
#pragma unroll
      for (int ot = 0; ot < 2; ++ot)
#pragma unroll
        for (int m = 0; m < 16; ++m) oacc[ot][m] *= a;
      mi = mnew;
    }
    float ls = 0.f;
#pragma unroll
    for (int s = 0; s < 2; ++s)
#pragma unroll
      for (int m = 0; m < 16; ++m) {
        const float p = EXP2(sa[s][m] - mi);
        sa[s][m] = p;
        ls += p;
      }
    li += ls;

    // pack P -> wave-private lP[q][key] (quad t holds keys s*32+8t+4hi+{0..3})
#pragma unroll
    for (int s = 0; s < 2; ++s)
#pragma unroll
      for (int t = 0; t < 4; ++t) {
        uint2 pw;
        pw.x = pkrtz(sa[s][4 * t + 0], sa[s][4 * t + 1]);
        pw.y = pkrtz(sa[s][4 * t + 2], sa[s][4 * t + 3]);
        *(uint2*)(lPw + q * 72 + s * 32 + t * 8 + hi * 4) = pw;
      }
    // B-frags: B[k=hi*8+e][col=q] for key-window w4 -> lP[q][w4*16+hi*8 ..]
    f16x8 bp[4];
#pragma unroll
    for (int w4 = 0; w4 < 4; ++w4)
      bp[w4] = *(const f16x8*)(lPw + q * 72 + w4 * 16 + hi * 8);

    // O^T += V^T x P : A = V^T[dim=ot*32+q][key win w4]
    __builtin_amdgcn_s_setprio(1);
#pragma unroll
    for (int w4 = 0; w4 < 4; ++w4)
#pragma unroll
      for (int ot = 0; ot < 2; ++ot) {
        f16x8 av = *(const f16x8*)(Vb + (ot * 32 + q) * 128 +
                                   (((w4 * 2 + hi) ^ (l & 7)) * 16));
        oacc[ot] = mfma32(av, bp[w4], oacc[ot]);
      }
    __builtin_amdgcn_s_setprio(0);
    cur ^= 1;
  }

  // epilogue: partner-sum li, store O^T rows (dims quad = 8t+4hi contiguous 4)
  li += __shfl_xor(li, 32);
  const int b = bh >> 4, h = bh & 15;
  const float inv = 1.0f / li;
  const size_t rowb = ((size_t)b * 2048 + qrow) * 1024 + h * 64;
#pragma unroll
  for (int ot = 0; ot < 2; ++ot)
#pragma unroll
    for (int t = 0; t < 4; ++t) {
      float4 o;
      o.x = oacc[ot][4 * t + 0] * inv;
      o.y = oacc[ot][4 * t + 1] * inv;
      o.z = oacc[ot][4 * t + 2] * inv;
      o.w = oacc[ot][4 * t + 3] * inv;
      *(float4*)(out + rowb + ot * 32 + t * 8 + hi * 4) = o;
    }
}

// ---------------------------------------------------------------------------
extern "C" void kernel_launch(void* const* d_in, const int* in_sizes, int n_in,
                              void* d_out, int out_size, void* d_ws, size_t ws_size,
                              hipStream_t stream) {
  const float* x     = (const float*)d_in[0];
  const float* w_qkv = (const float*)d_in[2];
  const float* b_qkv = (const float*)d_in[3];
  const float* w_rel = (const float*)d_in[4];
  const float* b_rel = (const float*)d_in[5];
  float* out = (float*)d_out;

  char* ws = (char*)d_ws;
  u16* xb    = (u16*)(ws);              // f16 x      [4096][1024]
  u16* wb    = (u16*)(ws +  8388608);   // f16 w_qkv  [3072][1024]
  u16* wrelb = (u16*)(ws + 14680064);   // f16 w_rel  [272][64]
  u16* qb    = (u16*)(ws + 14714880);   // q  [32][2048][64]
  u16* kb    = (u16*)(ws + 23103488);   // k  [32][2048][64]
  u16* vtb   = (u16*)(ws + 31492096);   // vT [32][64][2048]
  u16* relb  = (u16*)(ws + 39880704);   // rel[32][2048][257]
  u16* vb    = relb;                    // v row-major ALIASES relb (consumed
                                        // by vtrans before rel_proj writes)

  cvt_all<<<7185, 256, 0, stream>>>(x, w_qkv, w_rel, xb, wb, wrelb);
  qkv_gemm<<<768, 256, 0, stream>>>(xb, wb, b_qkv, qb, kb, vb);
  vtrans<<<512, 256, 0, stream>>>(vb, vtb);
  rel_proj<<<1024, 256, 0, stream>>>(qb, wrelb, b_rel, relb);
  attn_kernel<<<512, 256, 0, stream>>>(qb, kb, vtb, relb, out);
}